// Round 1
// baseline (160.436 us; speedup 1.0000x reference)
//
#include <hip/hip_runtime.h>

// SSIM (win=11, sigma=1.5, range=255), N=16 C=3 512x512 fp32 -> [16,502,502].
// R7: de-serialize the 5 quantities + kill LDS bank conflicts.
// R6 was latency-bound (MfmaUtil 6.7%, VALUBusy 18%, HBM 22%, Occ 23%):
// the single s_ht buffer forced write(q)->wait->read(q) RAW round-trips for
// each of the 5 quantities (15 exposed LDS round-trips per wave-channel),
// and HPITCH=48 f16 (24 dw, gcd(24,32)=8) made both the H-side ds_write_b64
// and V-side ds_read_b128 4-way bank-conflicted (SQ_LDS_BANK_CONFLICT 4.42M
// ~= 14% of kernel cycles) ON that critical chain.
// Fix:
//  * s_ht[5][TW][HPITCH]: per-quantity buffers. Phase H = all 15
//    mfma->cvt->ds_write back-to-back; Phase V = all 10 ds_read_b128->mfma
//    pipelined with fine-grained lgkmcnt. One LDS latency exposure per
//    channel instead of five. Still zero __syncthreads in the channel loop
//    (wave-private regions; per-wave DS in-order makes cross-channel reuse
//    safe, validated R3-R6).
//  * HPITCH = 56 f16 (112 B = 28 dw): 28r mod 32 + 4-dw-aligned spans tile
//    all 32 banks uniformly for BOTH b64 writes (4 lanes/bank = min) and
//    b128 reads (8 lanes/bank = min). Provably conflict-free.
//  * LDS 35.9 KB -> exactly 4 blocks/CU; __launch_bounds__(256,4) caps
//    VGPR<=128 so residency doubles vs R6 (~8 -> 16 waves/CU).
//  * V phase b-major: only 5 V-fragments live at once (20 VGPRs, not 40).
// No arithmetic change anywhere -> absmax must stay 0.0078125.
//
// Edge clamps (uniform min(), no scalar fallback): clamped cols/rows feed
// only zero band-weights or outputs masked at the store (unchanged from R6).
//
// MFMA scheme (mfma_f32_16x16x32_f16), B[k][n] = W[k-n] banded, both passes:
//  H: A[m=row][k=col] -> D[m=row][n=outcol]; C-layout (col=lane&15,
//     row=(lane>>4)*4+reg) -> ds_write_b64 transposed into H_T[outcol][row].
//  V: A[m=outcol][k=row] from H_T (k contiguous -> ds_read_b128),
//     D[m=outcol][n=outrow]. Wave owns outcol chunk for both passes.
//  x^2/y^2/xy A-frags derived in registers (v_pk_mul_f16 of x/y frags).

namespace {

constexpr int NN = 16, CC = 3, HH = 512, WW = 512;
constexpr int OH = HH - 10, OW = WW - 10;          // 502 x 502
constexpr int TW = 64, TH = 32;                    // output tile per block
constexpr int HPITCH = 56;                         // H_T row pitch (f16): 112 B = 28 dw
constexpr float C1c = 6.5025f;                     // (0.01*255)^2
constexpr float C2c = 58.5225f;                    // (0.03*255)^2

typedef _Float16 half8   __attribute__((ext_vector_type(8)));
typedef _Float16 half4   __attribute__((ext_vector_type(4)));
typedef float    floatv4 __attribute__((ext_vector_type(4)));

__device__ const float WF[11] = {
    0.00102838f, 0.00759876f, 0.03600077f, 0.10936069f, 0.21300553f,
    0.26601172f,
    0.21300553f, 0.10936069f, 0.03600077f, 0.00759876f, 0.00102838f
};

__device__ inline half8 pack8(const float4& a, const float4& b) {
    half8 h = {(_Float16)a.x, (_Float16)a.y, (_Float16)a.z, (_Float16)a.w,
               (_Float16)b.x, (_Float16)b.y, (_Float16)b.z, (_Float16)b.w};
    return h;
}

__global__ __launch_bounds__(256, 4)
void ssim_kernel(const float* __restrict__ X, const float* __restrict__ Y,
                 float* __restrict__ out)
{
    // 5 per-quantity transpose buffers: 5*64*56*2 = 35840 B (-> 4 blocks/CU)
    __shared__ __align__(16) _Float16 s_ht[5][TW][HPITCH];
    __shared__ _Float16 s_wtab[16];

    const int tid  = threadIdx.x;
    const int lane = tid & 63;
    const int wv   = tid >> 6;          // wave id = outcol chunk (16 cols)
    const int col0 = blockIdx.x * TW;
    const int row0 = blockIdx.y * TH;
    const int n    = blockIdx.z;

    if (tid < 16) s_wtab[tid] = (tid < 11) ? (_Float16)WF[tid] : (_Float16)0.f;
    __syncthreads();   // only block-wide sync in the kernel

    // banded weight fragment B[k][n] = W[k-n]; lane: n=lane&15, k=(lane>>4)*8+j
    half8 bfrag;
    {
        const int bn = lane & 15, kq = (lane >> 4) * 8;
        #pragma unroll
        for (int j = 0; j < 8; ++j) {
            int kk = kq + j - bn;
            kk = (kk < 0 || kk > 10) ? 11 : kk;   // index 11 holds 0
            bfrag[j] = s_wtab[kk];
        }
    }

    const int arow = lane & 15;          // A m-row select / V outrow-local
    const int aq   = lane >> 4;          // A k-quad
    const int crow = aq * 4;             // C-layout row base

    // global addresses for this lane's A-fragment loads (uniform clamps;
    // clamped lanes feed only zero-weight taps or masked-off outputs)
    int gcol = col0 + wv * 16 + aq * 8;
    gcol = gcol <= WW - 8 ? gcol : WW - 8;         // stays 32B-aligned
    int grow[3];
    #pragma unroll
    for (int rc = 0; rc < 3; ++rc) {
        int g = row0 + rc * 16 + arow;
        grow[rc] = g < HH ? g : HH - 1;
    }

    float acc[2][4] = {{0.f,0.f,0.f,0.f},{0.f,0.f,0.f,0.f}};

    const size_t plane = (size_t)HH * WW;
    const float* Xn = X + (size_t)n * CC * plane;
    const float* Yn = Y + (size_t)n * CC * plane;
    const floatv4 zf = {0.f, 0.f, 0.f, 0.f};

    for (int ch = 0; ch < CC; ++ch) {
        const float* Xc = Xn + (size_t)ch * plane;
        const float* Yc = Yn + (size_t)ch * plane;

        // ---- 12 independent dwordx4 loads: this wave's 3 rc x 32-col
        // A-regions for x and y ----
        float4 fx[3][2], fy[3][2];
        #pragma unroll
        for (int rc = 0; rc < 3; ++rc) {
            const float* bx = Xc + (size_t)grow[rc] * WW + gcol;
            const float* by = Yc + (size_t)grow[rc] * WW + gcol;
            fx[rc][0] = *(const float4*)bx;
            fx[rc][1] = *(const float4*)(bx + 4);
            fy[rc][0] = *(const float4*)by;
            fy[rc][1] = *(const float4*)(by + 4);
        }

        half8 axf[3], ayf[3];
        #pragma unroll
        for (int rc = 0; rc < 3; ++rc) {
            axf[rc] = pack8(fx[rc][0], fx[rc][1]);
            ayf[rc] = pack8(fy[rc][0], fy[rc][1]);
        }

        // ---- Phase H: all 15 H-MFMAs -> cvt -> ds_write_b64, no RAW
        // between them (per-q buffers). Chains are independent; the
        // compiler pipelines issue. ----
        #pragma unroll
        for (int q = 0; q < 5; ++q) {
            #pragma unroll
            for (int rc = 0; rc < 3; ++rc) {
                half8 a;
                if      (q == 0) a = axf[rc];
                else if (q == 1) a = ayf[rc];
                else if (q == 2) a = axf[rc] * axf[rc];
                else if (q == 3) a = ayf[rc] * ayf[rc];
                else             a = axf[rc] * ayf[rc];
                floatv4 d = __builtin_amdgcn_mfma_f32_16x16x32_f16(
                    a, bfrag, zf, 0, 0, 0);
                half4 h = {(_Float16)d[0], (_Float16)d[1],
                           (_Float16)d[2], (_Float16)d[3]};
                *(half4*)&s_ht[q][wv*16 + arow][rc*16 + crow] = h;
            }
        }

        // ---- Phase V + SSIM, b-major (only 5 V-frags live at once).
        // Per-wave DS in-order: these reads execute after the writes above;
        // only the MFMA consumption needs (fine-grained) lgkmcnt. ----
        #pragma unroll
        for (int b = 0; b < 2; ++b) {
            floatv4 v[5];
            #pragma unroll
            for (int q = 0; q < 5; ++q) {
                half8 av = *(const half8*)&s_ht[q][wv*16 + arow][b*16 + aq*8];
                v[q] = __builtin_amdgcn_mfma_f32_16x16x32_f16(
                    av, bfrag, zf, 0, 0, 0);
            }
            #pragma unroll
            for (int p = 0; p < 4; ++p) {
                float m1 = v[0][p], m2 = v[1][p];
                float exx = v[2][p], eyy = v[3][p], exy = v[4][p];
                float m1s = m1*m1, m2s = m2*m2, m12 = m1*m2;
                float s1 = exx - m1s, s2 = eyy - m2s, s12 = exy - m12;
                float n1 = 2.f*m12 + C1c, d1 = m1s + m2s + C1c;
                float n2 = 2.f*s12 + C2c, d2 = s1 + s2 + C2c;
                acc[b][p] = fmaf(n1 * n2, __builtin_amdgcn_rcpf(d1 * d2),
                                 acc[b][p]);
            }
        }
    }

    // ---- epilogue: 1 - mean over channels ----
    #pragma unroll
    for (int b = 0; b < 2; ++b) {
        const int orow = row0 + b*16 + arow;
        const int ocol = col0 + wv*16 + crow;
        if (orow < OH) {
            float r0v = 1.f - acc[b][0] * (1.f/3.f);
            float r1v = 1.f - acc[b][1] * (1.f/3.f);
            float r2v = 1.f - acc[b][2] * (1.f/3.f);
            float r3v = 1.f - acc[b][3] * (1.f/3.f);
            size_t base = ((size_t)n * OH + orow) * OW + ocol;
            if (ocol + 3 < OW) {
                *(float2*)(out + base)     = make_float2(r0v, r1v);
                *(float2*)(out + base + 2) = make_float2(r2v, r3v);
            } else {
                float rs[4] = {r0v, r1v, r2v, r3v};
                #pragma unroll
                for (int p = 0; p < 4; ++p)
                    if (ocol + p < OW) out[base + p] = rs[p];
            }
        }
    }
}

} // namespace

extern "C" void kernel_launch(void* const* d_in, const int* in_sizes, int n_in,
                              void* d_out, int out_size, void* d_ws, size_t ws_size,
                              hipStream_t stream) {
    const float* X = (const float*)d_in[0];
    const float* Y = (const float*)d_in[1];
    float* out = (float*)d_out;

    dim3 grid((OW + TW - 1) / TW,   // 8
              (OH + TH - 1) / TH,   // 16
              NN);                  // 16
    ssim_kernel<<<grid, 256, 0, stream>>>(X, Y, out);
}

// Round 2
// 148.939 us; speedup vs baseline: 1.0772x; 1.0772x over previous
//
#include <hip/hip_runtime.h>

// SSIM (win=11, sigma=1.5, range=255), N=16 C=3 512x512 fp32 -> [16,502,502].
// R8: channel-parallel waves. R6/R7 showed the kernel is latency-chain-bound
// (all pipes <25%): duration ~= (total waves / resident) * per-wave chain.
// R7's spill (VGPR cap 64 vs ~90 live) proved 3-channels-per-wave can't fit
// the 8-waves/SIMD occupancy bin. Fix: 384-thread blocks = 2 col-chunks x 3
// channels; each wave does ONE channel of a 16x32 tile (chain/3), 24576 waves
// total (3x), one-barrier LDS reduce for the channel mean.
// Register budget engineered for VGPR<=64 WITHOUT spill:
//  * q order {xy,xx,x,yy,y}: axf dies after q=2 -> only ayf (12) overlaps
//    vfr[5][2] (40). Peak ~53-61 by hand count.
//  * no channel loop, no carried acc (SSIM computed once from vfr).
//  * SGPR-base + voffset addressing (3 VGPRs).
//  * per-q ping-pong LDS buffers (q&1): write(q+1) provably independent of
//    read(q) -> compiler can overlap; same-buffer reuse (q+2) ordered by
//    per-wave DS in-order (validated R3-R7). Zero barriers in compute.
// HPITCH=56 f16 (28 dw) kept from R7: both ds_write_b64 (4/bank) and
// ds_read_b128 (8/bank) patterns are at the structural minimum.
// Channel sum order ch0+ch1+ch2 and per-channel math unchanged -> absmax
// must stay 0.0078125.
//
// Edge clamps: identical argument to R6/R7 (clamped cols/rows feed only
// zero band-weights or store-masked outputs); col clamp case col0=480,
// chunk=1 == R6's wv=3 case, proven.
//
// MFMA scheme (mfma_f32_16x16x32_f16), B[k][n] = W[k-n] banded, both passes:
//  H: A[m=row][k=col] -> D[m=row][n=outcol]; C-layout (col=lane&15,
//     row=(lane>>4)*4+reg) -> ds_write_b64 transposed into H_T[outcol][row].
//  V: A[m=outcol][k=row] from H_T (k contiguous -> ds_read_b128),
//     D[m=outcol][n=outrow].

namespace {

constexpr int NN = 16, CC = 3, HH = 512, WW = 512;
constexpr int OH = HH - 10, OW = WW - 10;          // 502 x 502
constexpr int TWB = 32, TH = 32;                   // output tile per block
constexpr int HP = 56;                             // H_T row pitch (f16)
constexpr float C1c = 6.5025f;                     // (0.01*255)^2
constexpr float C2c = 58.5225f;                    // (0.03*255)^2

typedef _Float16 half8   __attribute__((ext_vector_type(8)));
typedef _Float16 half4   __attribute__((ext_vector_type(4)));
typedef float    floatv4 __attribute__((ext_vector_type(4)));

__device__ const float WF[11] = {
    0.00102838f, 0.00759876f, 0.03600077f, 0.10936069f, 0.21300553f,
    0.26601172f,
    0.21300553f, 0.10936069f, 0.03600077f, 0.00759876f, 0.00102838f
};

__device__ inline half8 pack8(const float4& a, const float4& b) {
    half8 h = {(_Float16)a.x, (_Float16)a.y, (_Float16)a.z, (_Float16)a.w,
               (_Float16)b.x, (_Float16)b.y, (_Float16)b.z, (_Float16)b.w};
    return h;
}

__global__ __launch_bounds__(384, 8)
void ssim_kernel(const float* __restrict__ X, const float* __restrict__ Y,
                 float* __restrict__ out)
{
    // per-wave ping-pong transpose buffers: 6*2*16*56*2 = 21504 B
    __shared__ __align__(16) _Float16 s_ht[6][2][16][HP];
    // channel-partial reduce: [chunk][ch-1][lane][8 vals] = 8192 B
    __shared__ __align__(16) float    s_red[2][2][64][8];
    __shared__ _Float16 s_wtab[16];

    const int tid   = threadIdx.x;
    const int lane  = tid & 63;
    const int wv    = tid >> 6;         // 0..5
    const int chunk = wv / 3;           // 16-outcol slice within block
    const int ch    = wv % 3;           // channel this wave owns
    const int col0  = blockIdx.x * TWB;
    const int row0  = blockIdx.y * TH;
    const int n     = blockIdx.z;

    if (tid < 16) s_wtab[tid] = (tid < 11) ? (_Float16)WF[tid] : (_Float16)0.f;
    __syncthreads();

    const int arow = lane & 15;          // A m-row select / outrow-local
    const int aq   = lane >> 4;          // A k-quad
    const int crow = aq * 4;             // C-layout row base

    // per-lane voffsets (SGPR base + 32b offset addressing; 3 VGPRs)
    int gcol = col0 + chunk * 16 + aq * 8;
    gcol = gcol <= WW - 8 ? gcol : WW - 8;         // stays 32B-aligned
    int voff[3];
    #pragma unroll
    for (int rc = 0; rc < 3; ++rc) {
        int g = row0 + rc * 16 + arow;
        g = g < HH ? g : HH - 1;
        voff[rc] = g * WW + gcol;
    }

    const size_t plane = (size_t)HH * WW;
    const float* Xc = X + ((size_t)n * CC + ch) * plane;
    const float* Yc = Y + ((size_t)n * CC + ch) * plane;

    // ---- issue all 12 global loads first (latency overlap) ----
    float4 fx[3][2], fy[3][2];
    #pragma unroll
    for (int rc = 0; rc < 3; ++rc) {
        const float* bx = Xc + voff[rc];
        const float* by = Yc + voff[rc];
        fx[rc][0] = *(const float4*)bx;
        fx[rc][1] = *(const float4*)(bx + 4);
        fy[rc][0] = *(const float4*)by;
        fy[rc][1] = *(const float4*)(by + 4);
    }

    // banded weight fragment B[k][n] = W[k-n] (LDS reads overlap the
    // in-flight global loads)
    half8 bfrag;
    {
        const int bn = lane & 15, kq = aq * 8;
        #pragma unroll
        for (int j = 0; j < 8; ++j) {
            int kk = kq + j - bn;
            kk = (kk < 0 || kk > 10) ? 11 : kk;   // index 11 holds 0
            bfrag[j] = s_wtab[kk];
        }
    }

    half8 axf[3], ayf[3];
    #pragma unroll
    for (int rc = 0; rc < 3; ++rc) {
        axf[rc] = pack8(fx[rc][0], fx[rc][1]);
        ayf[rc] = pack8(fy[rc][0], fy[rc][1]);
    }

    const floatv4 zf = {0.f, 0.f, 0.f, 0.f};

    // q order {xy, xx, x, yy, y}: axf dead after qi==2 -> lowers peak
    // register pressure while vfr[] grows.
    floatv4 vfr[5][2];
    #pragma unroll
    for (int qi = 0; qi < 5; ++qi) {
        #pragma unroll
        for (int rc = 0; rc < 3; ++rc) {
            half8 a;
            if      (qi == 0) a = axf[rc] * ayf[rc];   // xy
            else if (qi == 1) a = axf[rc] * axf[rc];   // xx
            else if (qi == 2) a = axf[rc];             // x  (last axf use)
            else if (qi == 3) a = ayf[rc] * ayf[rc];   // yy
            else              a = ayf[rc];             // y
            floatv4 d = __builtin_amdgcn_mfma_f32_16x16x32_f16(
                a, bfrag, zf, 0, 0, 0);
            half4 h = {(_Float16)d[0], (_Float16)d[1],
                       (_Float16)d[2], (_Float16)d[3]};
            *(half4*)&s_ht[wv][qi & 1][arow][rc * 16 + crow] = h;
        }
        #pragma unroll
        for (int b = 0; b < 2; ++b) {
            half8 av = *(const half8*)&s_ht[wv][qi & 1][arow][b * 16 + aq * 8];
            vfr[qi][b] = __builtin_amdgcn_mfma_f32_16x16x32_f16(
                av, bfrag, zf, 0, 0, 0);
        }
    }

    // ---- SSIM from V fragments (vfr: 0=xy 1=xx 2=x 3=yy 4=y) ----
    float res[2][4];
    #pragma unroll
    for (int b = 0; b < 2; ++b) {
        #pragma unroll
        for (int p = 0; p < 4; ++p) {
            float m1 = vfr[2][b][p], m2 = vfr[4][b][p];
            float exx = vfr[1][b][p], eyy = vfr[3][b][p],
                  exy = vfr[0][b][p];
            float m1s = m1*m1, m2s = m2*m2, m12 = m1*m2;
            float s1 = exx - m1s, s2 = eyy - m2s, s12 = exy - m12;
            float n1 = 2.f*m12 + C1c, d1 = m1s + m2s + C1c;
            float n2 = 2.f*s12 + C2c, d2 = s1 + s2 + C2c;
            res[b][p] = fmaf(n1 * n2, __builtin_amdgcn_rcpf(d1 * d2), 0.f);
        }
    }

    // ---- cross-wave channel reduce (one barrier) ----
    if (ch != 0) {
        *(float4*)&s_red[chunk][ch - 1][lane][0] =
            make_float4(res[0][0], res[0][1], res[0][2], res[0][3]);
        *(float4*)&s_red[chunk][ch - 1][lane][4] =
            make_float4(res[1][0], res[1][1], res[1][2], res[1][3]);
    }
    __syncthreads();

    if (ch == 0) {
        // sum order ch0 + ch1 + ch2 (matches R6's accumulation order)
        #pragma unroll
        for (int cc = 0; cc < 2; ++cc) {
            float4 r0 = *(const float4*)&s_red[chunk][cc][lane][0];
            float4 r1 = *(const float4*)&s_red[chunk][cc][lane][4];
            res[0][0] += r0.x; res[0][1] += r0.y;
            res[0][2] += r0.z; res[0][3] += r0.w;
            res[1][0] += r1.x; res[1][1] += r1.y;
            res[1][2] += r1.z; res[1][3] += r1.w;
        }
        // ---- epilogue: 1 - mean over channels ----
        #pragma unroll
        for (int b = 0; b < 2; ++b) {
            const int orow = row0 + b * 16 + arow;
            const int ocol = col0 + chunk * 16 + crow;
            if (orow < OH) {
                float r0v = 1.f - res[b][0] * (1.f/3.f);
                float r1v = 1.f - res[b][1] * (1.f/3.f);
                float r2v = 1.f - res[b][2] * (1.f/3.f);
                float r3v = 1.f - res[b][3] * (1.f/3.f);
                size_t base = ((size_t)n * OH + orow) * OW + ocol;
                if (ocol + 3 < OW) {
                    *(float2*)(out + base)     = make_float2(r0v, r1v);
                    *(float2*)(out + base + 2) = make_float2(r2v, r3v);
                } else {
                    float rs[4] = {r0v, r1v, r2v, r3v};
                    #pragma unroll
                    for (int p = 0; p < 4; ++p)
                        if (ocol + p < OW) out[base + p] = rs[p];
                }
            }
        }
    }
}

} // namespace

extern "C" void kernel_launch(void* const* d_in, const int* in_sizes, int n_in,
                              void* d_out, int out_size, void* d_ws, size_t ws_size,
                              hipStream_t stream) {
    const float* X = (const float*)d_in[0];
    const float* Y = (const float*)d_in[1];
    float* out = (float*)d_out;

    dim3 grid((OW + TWB - 1) / TWB,   // 16
              (OH + TH  - 1) / TH,    // 16
              NN);                    // 16
    ssim_kernel<<<grid, 384, 0, stream>>>(X, Y, out);
}

// Round 3
// 142.149 us; speedup vs baseline: 1.1286x; 1.0478x over previous
//
#include <hip/hip_runtime.h>

// SSIM (win=11, sigma=1.5, range=255), N=16 C=3 512x512 fp32 -> [16,502,502].
// R9: revert to the proven R6 skeleton (best measured: 52.6us/dispatch) and
// apply exactly three attributable fixes. R7 (per-q buffers + occupancy push)
// spilled and regressed; R8 (channel-parallel waves) tripled per-wave fixed
// overhead and regressed despite 47% occupancy. Conclusion from R6-R8:
// occupancy is NOT the limiting resource; per-wave issued work + exposed
// chain latency is. So: keep R6's 4-wave 64x32 tile, 3-channel loop, zero
// compute barriers, and surgically cut the three identified chain costs:
//  1. HPITCH 48->56 f16 (112 B = 28 dw): R6's 24-dw pitch (gcd 8 with 32
//     banks) made H ds_write_b64 and V ds_read_b128 4-way conflicted
//     (SQ_LDS_BANK_CONFLICT 4.42M cyc ~= 13% of kernel, ON the RAW chain).
//     At 28 dw both patterns are at the structural minimum (verified:
//     write 4 acc/bank, read 8 acc/bank, uniform). R7/R8 confirmed ~2x drop.
//  2. Ping-pong s_ht[2][64][56] (14.3 KB): write(q+1) no longer aliases
//     read(q) -> compiler can overlap adjacent q-chains instead of
//     serializing 5 LDS round-trips (R6's single buffer). Same-buffer reuse
//     at distance 2 ordered by per-wave DS in-order (validated R3-R8).
//  3. Next-channel register prefetch: issue ch+1's 12 dwordx4 loads right
//     after ch's fx/fy are consumed into f16 packs -> the ~900cy HBM
//     latency hides under ch's 25 MFMAs + SSIM instead of being exposed 3x
//     serially. q order {xy,xx,x,yy,y} retires axf before vfr[] peaks.
//     Hand count ~108 VGPR < 128 cap of (256,2). Tripwire: WRITE_SIZE
//     >25MB = spill, revert.
// Channel sum order and per-output arithmetic identical to R6 -> absmax
// must stay 0.0078125.
//
// Edge clamps (uniform min(), no scalar fallback): clamped cols/rows feed
// only zero band-weights (staged row r feeds outrow n iff 0<=r-n<=10) or
// outputs masked at the store (unchanged from R6).
//
// MFMA scheme (mfma_f32_16x16x32_f16), B[k][n] = W[k-n] banded, both passes:
//  H: A[m=row][k=col] -> D[m=row][n=outcol]; C-layout (col=lane&15,
//     row=(lane>>4)*4+reg) -> ds_write_b64 transposed into H_T[outcol][row].
//  V: A[m=outcol][k=row] from H_T (k contiguous -> ds_read_b128),
//     D[m=outcol][n=outrow]. Wave owns outcol chunk for both passes.
//  x^2/y^2/xy A-frags derived in registers (v_pk_mul_f16 of x/y frags).

namespace {

constexpr int NN = 16, CC = 3, HH = 512, WW = 512;
constexpr int OH = HH - 10, OW = WW - 10;          // 502 x 502
constexpr int TW = 64, TH = 32;                    // output tile per block
constexpr int HPITCH = 56;                         // H_T row pitch (f16): 28 dw
constexpr float C1c = 6.5025f;                     // (0.01*255)^2
constexpr float C2c = 58.5225f;                    // (0.03*255)^2

typedef _Float16 half8   __attribute__((ext_vector_type(8)));
typedef _Float16 half4   __attribute__((ext_vector_type(4)));
typedef float    floatv4 __attribute__((ext_vector_type(4)));

__device__ const float WF[11] = {
    0.00102838f, 0.00759876f, 0.03600077f, 0.10936069f, 0.21300553f,
    0.26601172f,
    0.21300553f, 0.10936069f, 0.03600077f, 0.00759876f, 0.00102838f
};

__device__ inline half8 pack8(const float4& a, const float4& b) {
    half8 h = {(_Float16)a.x, (_Float16)a.y, (_Float16)a.z, (_Float16)a.w,
               (_Float16)b.x, (_Float16)b.y, (_Float16)b.z, (_Float16)b.w};
    return h;
}

__global__ __launch_bounds__(256, 2)
void ssim_kernel(const float* __restrict__ X, const float* __restrict__ Y,
                 float* __restrict__ out)
{
    // ping-pong transpose buffers: 2*64*56*2 = 14336 B
    __shared__ __align__(16) _Float16 s_ht[2][TW][HPITCH];
    __shared__ _Float16 s_wtab[16];

    const int tid  = threadIdx.x;
    const int lane = tid & 63;
    const int wv   = tid >> 6;          // wave id = outcol chunk (16 cols)
    const int col0 = blockIdx.x * TW;
    const int row0 = blockIdx.y * TH;
    const int n    = blockIdx.z;

    if (tid < 16) s_wtab[tid] = (tid < 11) ? (_Float16)WF[tid] : (_Float16)0.f;
    __syncthreads();   // only block-wide sync in the kernel

    // banded weight fragment B[k][n] = W[k-n]; lane: n=lane&15, k=(lane>>4)*8+j
    half8 bfrag;
    {
        const int bn = lane & 15, kq = (lane >> 4) * 8;
        #pragma unroll
        for (int j = 0; j < 8; ++j) {
            int kk = kq + j - bn;
            kk = (kk < 0 || kk > 10) ? 11 : kk;   // index 11 holds 0
            bfrag[j] = s_wtab[kk];
        }
    }

    const int arow = lane & 15;          // A m-row select / V outrow-local
    const int aq   = lane >> 4;          // A k-quad
    const int crow = aq * 4;             // C-layout row base

    // global addresses for this lane's A-fragment loads (uniform clamps;
    // clamped lanes feed only zero-weight taps or masked-off outputs)
    int gcol = col0 + wv * 16 + aq * 8;
    gcol = gcol <= WW - 8 ? gcol : WW - 8;         // stays 32B-aligned
    int grow[3];
    #pragma unroll
    for (int rc = 0; rc < 3; ++rc) {
        int g = row0 + rc * 16 + arow;
        grow[rc] = g < HH ? g : HH - 1;
    }

    float acc[2][4] = {{0.f,0.f,0.f,0.f},{0.f,0.f,0.f,0.f}};

    const size_t plane = (size_t)HH * WW;
    const float* Xn = X + (size_t)n * CC * plane;
    const float* Yn = Y + (size_t)n * CC * plane;
    const floatv4 zf = {0.f, 0.f, 0.f, 0.f};

    // ---- prologue: issue channel 0's 12 independent dwordx4 loads ----
    float4 fx[3][2], fy[3][2];
    #pragma unroll
    for (int rc = 0; rc < 3; ++rc) {
        const float* bx = Xn + (size_t)grow[rc] * WW + gcol;
        const float* by = Yn + (size_t)grow[rc] * WW + gcol;
        fx[rc][0] = *(const float4*)bx;
        fx[rc][1] = *(const float4*)(bx + 4);
        fy[rc][0] = *(const float4*)by;
        fy[rc][1] = *(const float4*)(by + 4);
    }

    for (int ch = 0; ch < CC; ++ch) {
        // consume fx/fy into f16 packs, freeing them as prefetch targets
        half8 axf[3], ayf[3];
        #pragma unroll
        for (int rc = 0; rc < 3; ++rc) {
            axf[rc] = pack8(fx[rc][0], fx[rc][1]);
            ayf[rc] = pack8(fy[rc][0], fy[rc][1]);
        }

        // ---- prefetch ch+1's loads: latency hides under this channel's
        // 25 MFMAs + SSIM (uniform branch, no divergence) ----
        if (ch + 1 < CC) {
            const float* Xc = Xn + (size_t)(ch + 1) * plane;
            const float* Yc = Yn + (size_t)(ch + 1) * plane;
            #pragma unroll
            for (int rc = 0; rc < 3; ++rc) {
                const float* bx = Xc + (size_t)grow[rc] * WW + gcol;
                const float* by = Yc + (size_t)grow[rc] * WW + gcol;
                fx[rc][0] = *(const float4*)bx;
                fx[rc][1] = *(const float4*)(bx + 4);
                fy[rc][0] = *(const float4*)by;
                fy[rc][1] = *(const float4*)(by + 4);
            }
        }

        // ---- H + V MFMA per quantity, ping-pong buffer [qi&1]:
        // write(q+1) independent of read(q) -> chains overlap. q order
        // {xy,xx,x,yy,y} retires axf before vfr[] peaks. ----
        floatv4 vfr[5][2];
        #pragma unroll
        for (int qi = 0; qi < 5; ++qi) {
            #pragma unroll
            for (int rc = 0; rc < 3; ++rc) {
                half8 a;
                if      (qi == 0) a = axf[rc] * ayf[rc];   // xy
                else if (qi == 1) a = axf[rc] * axf[rc];   // xx
                else if (qi == 2) a = axf[rc];             // x (last axf use)
                else if (qi == 3) a = ayf[rc] * ayf[rc];   // yy
                else              a = ayf[rc];             // y
                floatv4 d = __builtin_amdgcn_mfma_f32_16x16x32_f16(
                    a, bfrag, zf, 0, 0, 0);
                half4 h = {(_Float16)d[0], (_Float16)d[1],
                           (_Float16)d[2], (_Float16)d[3]};
                *(half4*)&s_ht[qi & 1][wv*16 + arow][rc*16 + crow] = h;
            }
            #pragma unroll
            for (int b = 0; b < 2; ++b) {
                half8 av = *(const half8*)
                    &s_ht[qi & 1][wv*16 + arow][b*16 + aq*8];
                vfr[qi][b] = __builtin_amdgcn_mfma_f32_16x16x32_f16(
                    av, bfrag, zf, 0, 0, 0);
            }
        }

        // ---- SSIM on V fragments (vfr: 0=xy 1=xx 2=x 3=yy 4=y) ----
        #pragma unroll
        for (int b = 0; b < 2; ++b) {
            #pragma unroll
            for (int p = 0; p < 4; ++p) {
                float m1 = vfr[2][b][p], m2 = vfr[4][b][p];
                float exx = vfr[1][b][p], eyy = vfr[3][b][p],
                      exy = vfr[0][b][p];
                float m1s = m1*m1, m2s = m2*m2, m12 = m1*m2;
                float s1 = exx - m1s, s2 = eyy - m2s, s12 = exy - m12;
                float n1 = 2.f*m12 + C1c, d1 = m1s + m2s + C1c;
                float n2 = 2.f*s12 + C2c, d2 = s1 + s2 + C2c;
                acc[b][p] = fmaf(n1 * n2, __builtin_amdgcn_rcpf(d1 * d2),
                                 acc[b][p]);
            }
        }
    }

    // ---- epilogue: 1 - mean over channels ----
    #pragma unroll
    for (int b = 0; b < 2; ++b) {
        const int orow = row0 + b*16 + arow;
        const int ocol = col0 + wv*16 + crow;
        if (orow < OH) {
            float r0v = 1.f - acc[b][0] * (1.f/3.f);
            float r1v = 1.f - acc[b][1] * (1.f/3.f);
            float r2v = 1.f - acc[b][2] * (1.f/3.f);
            float r3v = 1.f - acc[b][3] * (1.f/3.f);
            size_t base = ((size_t)n * OH + orow) * OW + ocol;
            if (ocol + 3 < OW) {
                *(float2*)(out + base)     = make_float2(r0v, r1v);
                *(float2*)(out + base + 2) = make_float2(r2v, r3v);
            } else {
                float rs[4] = {r0v, r1v, r2v, r3v};
                #pragma unroll
                for (int p = 0; p < 4; ++p)
                    if (ocol + p < OW) out[base + p] = rs[p];
            }
        }
    }
}

} // namespace

extern "C" void kernel_launch(void* const* d_in, const int* in_sizes, int n_in,
                              void* d_out, int out_size, void* d_ws, size_t ws_size,
                              hipStream_t stream) {
    const float* X = (const float*)d_in[0];
    const float* Y = (const float*)d_in[1];
    float* out = (float*)d_out;

    dim3 grid((OW + TW - 1) / TW,   // 8
              (OH + TH - 1) / TH,   // 16
              NN);                  // 16
    ssim_kernel<<<grid, 256, 0, stream>>>(X, Y, out);
}